// Round 17
// baseline (352.571 us; speedup 1.0000x reference)
//
#include <hip/hip_runtime.h>
#include <hip/hip_cooperative_groups.h>

namespace cg = cooperative_groups;

#define NN 100000
#define NE 1600000
#define NG 64
#define BPB  50
#define NBUK 2000
#define NBUK2 2048
#define ECAP 1152
#define GPART 256
#define NSLICE 8
#define SLB (GPART/NSLICE)
#define PREPB 128
#define ZEROB 3
#define GSTB ((NN+255)/256)

using bf16x8 = __attribute__((ext_vector_type(8))) short;
using f32x4  = __attribute__((ext_vector_type(4))) float;

__device__ inline unsigned short f2bf(float f){
    union { float f; unsigned u; } v; v.f = f;
    unsigned r = (v.u + 0x7FFFu + ((v.u >> 16) & 1u)) >> 16;
    return (unsigned short)r;
}

__device__ inline bf16x8 cvt8(f32x4 a, f32x4 b){
    union { unsigned u[4]; bf16x8 v; } r;
    asm("v_cvt_pk_bf16_f32 %0, %1, %2" : "=v"(r.u[0]) : "v"(a[0]), "v"(a[1]));
    asm("v_cvt_pk_bf16_f32 %0, %1, %2" : "=v"(r.u[1]) : "v"(a[2]), "v"(a[3]));
    asm("v_cvt_pk_bf16_f32 %0, %1, %2" : "=v"(r.u[2]) : "v"(b[0]), "v"(b[1]));
    asm("v_cvt_pk_bf16_f32 %0, %1, %2" : "=v"(r.u[3]) : "v"(b[2]), "v"(b[3]));
    return r.v;
}

// ---------------- k_start: count (int4) + prepw + zero + gstart ----------------
__global__ __launch_bounds__(256) void k_start(const int* __restrict__ src, const int* __restrict__ dst,
                                               int* __restrict__ cntD, int* __restrict__ cntS, int E,
                                               const float* __restrict__ W1, short* __restrict__ Wb,
                                               float* __restrict__ pooled,
                                               unsigned short* __restrict__ hb, float* __restrict__ h2,
                                               const int* __restrict__ n2g, int* __restrict__ gstart, int N){
    __shared__ int hD[NBUK2], hS[NBUK2];
    int bid = blockIdx.x;
    int tid = threadIdx.x;
    if (bid < GPART){
        for (int i=tid; i<NBUK2; i+=256){ hD[i]=0; hS[i]=0; }
        __syncthreads();
        int EV = E >> 2;
        int chunkV = (EV + GPART - 1)/GPART;
        int sV = bid*chunkV, eV = min(EV, sV+chunkV);
        for (int v = sV + tid; v < eV; v += 256){
            int4 s4 = ((const int4*)src)[v];
            int4 d4 = ((const int4*)dst)[v];
            atomicAdd(&hS[s4.x/BPB], 1); atomicAdd(&hS[s4.y/BPB], 1);
            atomicAdd(&hS[s4.z/BPB], 1); atomicAdd(&hS[s4.w/BPB], 1);
            atomicAdd(&hD[d4.x/BPB], 1); atomicAdd(&hD[d4.y/BPB], 1);
            atomicAdd(&hD[d4.z/BPB], 1); atomicAdd(&hD[d4.w/BPB], 1);
        }
        __syncthreads();
        for (int i=tid; i<NBUK2; i+=256){
            cntD[bid*NBUK2 + i] = hD[i];
            cntS[bid*NBUK2 + i] = hS[i];
        }
    } else if (bid < GPART+PREPB){
        int i = (bid-GPART)*256 + tid;
        if (i < 512*64){
            int k = i >> 6, c = i & 63;
            int g = k >> 5, r = k & 31, s = r >> 3, j = r & 7;
            Wb[(((g*4+s)*64 + c) << 3) + j] = (short)f2bf(W1[i]);
        }
    } else if (bid < GPART+PREPB+ZEROB){
        int i = (bid-GPART-PREPB)*256 + tid;
        if (i < NG*10) pooled[i] = 0.f;
        else if (i < NG*10 + 64) hb[(size_t)N*64 + (i - NG*10)] = 0;
        else if (i < NG*10 + 64 + 16) h2[(size_t)N*16 + (i - NG*10 - 64)] = 0.f;
    } else {
        int n = (bid-GPART-PREPB-ZEROB)*256 + tid;
        if (n < N){
            int g  = n2g[n];
            int gp = (n == 0) ? -1 : n2g[n-1];
            if (gp != g){
                for (int gg = gp+1; gg <= g; ++gg) gstart[gg] = n;
            }
            if (n == N-1){
                for (int gg = g+1; gg <= NG; ++gg) gstart[gg] = N;
            }
        }
    }
}

// ---------------- k_mid (cooperative): scanCa | scanB | scanCb | scatter | outdeg ----------------
__global__ __launch_bounds__(256) void k_mid(int* __restrict__ cntD, int* __restrict__ cntS,
                                             int* __restrict__ sliceD, int* __restrict__ sliceS,
                                             int* __restrict__ bstartD, int* __restrict__ bstartS,
                                             const int* __restrict__ src, const int* __restrict__ dst,
                                             int* __restrict__ pairs, unsigned char* __restrict__ srcb,
                                             float* __restrict__ sn, int E, int N){
    cg::grid_group grid = cg::this_grid();
    __shared__ int shm[NBUK2*2];
    int bid = blockIdx.x;
    int tid = threadIdx.x;

    // phase 1: scanCa (64 blocks)
    if (bid < 64){
        int id = bid*256 + tid;
        int t = id & (NBUK2-1);
        int s = id >> 11;
        int b0 = s*SLB;
        int sD=0, sS=0;
        for (int b=b0; b<b0+SLB; b++){ sD += cntD[b*NBUK2+t]; sS += cntS[b*NBUK2+t]; }
        sliceD[s*NBUK2+t] = sD;
        sliceS[s*NBUK2+t] = sS;
    }
    grid.sync();

    // phase 2: scanB (block 0, 256 threads; 8 buckets/thread)
    if (bid == 0){
        int vD[8], vS[8];
        int LD=0, LS=0;
        #pragma unroll
        for (int k=0;k<8;k++){
            int t = tid*8+k;
            int d=0, s=0;
            #pragma unroll
            for (int sp=0;sp<NSLICE;sp++){ d += sliceD[sp*NBUK2+t]; s += sliceS[sp*NBUK2+t]; }
            vD[k]=d; vS[k]=s; LD+=d; LS+=s;
        }
        shm[tid] = LD; __syncthreads();
        for (int off=1; off<256; off<<=1){
            int t2 = (tid>=off)? shm[tid-off]:0; __syncthreads();
            shm[tid]+=t2; __syncthreads();
        }
        int baseD = shm[tid]-LD;
        __syncthreads();
        shm[tid] = LS; __syncthreads();
        for (int off=1; off<256; off<<=1){
            int t2=(tid>=off)? shm[tid-off]:0; __syncthreads();
            shm[tid]+=t2; __syncthreads();
        }
        int baseS = shm[tid]-LS;
        int rD=baseD, rS=baseS;
        #pragma unroll
        for (int k=0;k<8;k++){
            int t = tid*8+k;
            if (t<=NBUK){ bstartD[t]=rD; bstartS[t]=rS; }
            rD+=vD[k]; rS+=vS[k];
        }
    }
    grid.sync();

    // phase 3: scanCb (64 blocks)
    if (bid < 64){
        int id = bid*256 + tid;
        int t = id & (NBUK2-1);
        int s = id >> 11;
        if (t < NBUK){
            int rD = bstartD[t], rS = bstartS[t];
            for (int sp=0; sp<s; sp++){ rD += sliceD[sp*NBUK2+t]; rS += sliceS[sp*NBUK2+t]; }
            int b0 = s*SLB;
            for (int b=b0; b<b0+SLB; b++){
                int idx = b*NBUK2 + t;
                int o = cntD[idx]; cntD[idx] = rD; rD += o;
                o = cntS[idx];     cntS[idx] = rS; rS += o;
            }
        }
    }
    grid.sync();

    // phase 4: scatter (all 256 blocks)
    {
        int* oD = shm;
        int* oS = shm + NBUK2;
        for (int i=tid; i<NBUK2; i+=256){
            oD[i] = cntD[bid*NBUK2 + i];
            oS[i] = cntS[bid*NBUK2 + i];
        }
        __syncthreads();
        int EV = E >> 2;
        int chunkV = (EV + GPART - 1)/GPART;
        int sV = bid*chunkV, eV = min(EV, sV+chunkV);
        for (int v = sV + tid; v < eV; v += 256){
            int4 s4 = ((const int4*)src)[v];
            int4 d4 = ((const int4*)dst)[v];
            #pragma unroll
            for (int k=0;k<4;k++){
                int s = (k==0)?s4.x:(k==1)?s4.y:(k==2)?s4.z:s4.w;
                int d = (k==0)?d4.x:(k==1)?d4.y:(k==2)?d4.z:d4.w;
                int bk = d/BPB;
                int pD = atomicAdd(&oD[bk], 1);
                pairs[pD] = (s << 6) | (d - bk*BPB);
                int sb = s/BPB;
                int pS = atomicAdd(&oS[sb], 1);
                srcb[pS] = (unsigned char)(s - sb*BPB);
            }
        }
    }
    grid.sync();

    // phase 5: outdeg (grid-stride buckets)
    for (int b = bid; b < NBUK; b += gridDim.x){
        if (tid < BPB) shm[tid] = 0;
        __syncthreads();
        int s0 = bstartS[b], s1 = bstartS[b+1];
        for (int i = s0 + tid; i < s1; i += 256)
            atomicAdd(&shm[srcb[i]], 1);
        __syncthreads();
        int node = b*BPB + tid;
        if (tid < BPB && node < N)
            sn[node] = rsqrtf((float)max(shm[tid], 1));
        __syncthreads();
    }
}

// ---------------- GEMM1 (MFMA bf16): hb = (x @ W1) * sn; 32 rows/wave; nt x loads ----------------
__global__ __launch_bounds__(256) void k_gemm1(const float* __restrict__ x, const short* __restrict__ Wb,
                                               const float* __restrict__ sn, unsigned short* __restrict__ hb, int N){
    const int lane = threadIdx.x & 63;
    const int wid  = threadIdx.x >> 6;
    const int rowBase = blockIdx.x*128 + wid*32;
    const int mrow = lane & 15;
    const int s    = lane >> 4;

    int rowA = rowBase + mrow;
    int rowB = rowBase + 16 + mrow;
    int rcA = (rowA < N) ? rowA : (N-1);
    int rcB = (rowB < N) ? rowB : (N-1);

    const f32x4* __restrict__ xv = (const f32x4*)x;
    const bf16x8* __restrict__ wv = (const bf16x8*)Wb;
    const f32x4* xrA = xv + (size_t)rcA*128 + s*2;
    const f32x4* xrB = xv + (size_t)rcB*128 + s*2;

    f32x4 accA0 = {0,0,0,0}, accA1 = {0,0,0,0}, accA2 = {0,0,0,0}, accA3 = {0,0,0,0};
    f32x4 accB0 = {0,0,0,0}, accB1 = {0,0,0,0}, accB2 = {0,0,0,0}, accB3 = {0,0,0,0};

    #pragma unroll 2
    for (int g=0; g<16; g++){
        f32x4 a0 = __builtin_nontemporal_load(xrA + g*8 + 0);
        f32x4 a1 = __builtin_nontemporal_load(xrA + g*8 + 1);
        f32x4 c0 = __builtin_nontemporal_load(xrB + g*8 + 0);
        f32x4 c1 = __builtin_nontemporal_load(xrB + g*8 + 1);
        bf16x8 afA = cvt8(a0, a1);
        bf16x8 afB = cvt8(c0, c1);
        int bbase = (g*4 + s)*64 + mrow;
        bf16x8 b0 = wv[bbase     ];
        bf16x8 b1 = wv[bbase + 16];
        bf16x8 b2 = wv[bbase + 32];
        bf16x8 b3 = wv[bbase + 48];
        accA0 = __builtin_amdgcn_mfma_f32_16x16x32_bf16(afA, b0, accA0, 0, 0, 0);
        accA1 = __builtin_amdgcn_mfma_f32_16x16x32_bf16(afA, b1, accA1, 0, 0, 0);
        accA2 = __builtin_amdgcn_mfma_f32_16x16x32_bf16(afA, b2, accA2, 0, 0, 0);
        accA3 = __builtin_amdgcn_mfma_f32_16x16x32_bf16(afA, b3, accA3, 0, 0, 0);
        accB0 = __builtin_amdgcn_mfma_f32_16x16x32_bf16(afB, b0, accB0, 0, 0, 0);
        accB1 = __builtin_amdgcn_mfma_f32_16x16x32_bf16(afB, b1, accB1, 0, 0, 0);
        accB2 = __builtin_amdgcn_mfma_f32_16x16x32_bf16(afB, b2, accB2, 0, 0, 0);
        accB3 = __builtin_amdgcn_mfma_f32_16x16x32_bf16(afB, b3, accB3, 0, 0, 0);
    }

    #pragma unroll
    for (int q=0; q<4; q++){
        int rr = rowBase + s*4 + q;
        if (rr < N){
            float scale = sn[rr];
            unsigned short* hp = hb + ((size_t)rr<<6) + mrow;
            hp[ 0] = f2bf(accA0[q] * scale);
            hp[16] = f2bf(accA1[q] * scale);
            hp[32] = f2bf(accA2[q] * scale);
            hp[48] = f2bf(accA3[q] * scale);
        }
        int r2 = rowBase + 16 + s*4 + q;
        if (r2 < N){
            float scale = sn[r2];
            unsigned short* hp = hb + ((size_t)r2<<6) + mrow;
            hp[ 0] = f2bf(accB0[q] * scale);
            hp[16] = f2bf(accB1[q] * scale);
            hp[32] = f2bf(accB2[q] * scale);
            hp[48] = f2bf(accB3[q] * scale);
        }
    }
}

// ---------------- phase D: padded CSR-in-LDS gather + LDS GEMM2 (512 threads) ----------------
__global__ __launch_bounds__(512) void k_agg(const int* __restrict__ pairs, const int* __restrict__ bstartD,
                                             const unsigned short* __restrict__ hb,
                                             const float* __restrict__ sn, const float* __restrict__ b1,
                                             const float* __restrict__ W2,
                                             float* __restrict__ h2, int* __restrict__ gsrc,
                                             int* __restrict__ glh, int N){
    __shared__ int lsrc[ECAP];
    __shared__ int lcnt[BPB];
    __shared__ int lstart[BPB+1];
    __shared__ unsigned lofs[BPB];
    __shared__ __align__(16) float w2t[10][64];
    __shared__ float b1s[64];
    __shared__ __align__(16) float a1s[BPB][68];
    int tid = threadIdx.x;
    if (tid < BPB) lcnt[tid] = 0;
    if (tid < 64)  b1s[tid] = b1[tid];
    for (int i=tid; i<ECAP; i+=512) lsrc[i] = N;
    for (int i=tid; i<640; i+=512){ int c = i>>6, k = i&63; w2t[c][k] = W2[k*10 + c]; }
    __syncthreads();

    int b = blockIdx.x;
    int nodeBase = b*BPB;
    int eb = bstartD[b], ee = bstartD[b+1];
    int ne = ee - eb;

    for (int i = tid; i < ne; i += 512){
        int pr = pairs[eb + i];
        atomicAdd(&lcnt[pr & 63], 1);
    }
    __syncthreads();
    if (tid < 64){
        int mt = (tid < BPB) ? lcnt[tid] : 0;
        int v = (mt + 3) & ~3;
        int sI = v;
        for (int off=1; off<64; off<<=1){
            int t = __shfl_up(sI, off);
            if (tid >= off) sI += t;
        }
        if (tid < BPB){
            lstart[tid] = sI - v;
            lofs[tid]   = (unsigned)(sI - v);
            if (tid == BPB-1) lstart[BPB] = sI;
        }
    }
    __syncthreads();
    for (int i = tid; i < ne; i += 512){
        int pr = pairs[eb + i];
        unsigned pos = atomicAdd(&lofs[pr & 63], 1u);
        lsrc[pos < ECAP ? pos : ECAP-1] = pr >> 6;
    }
    __syncthreads();

    int ptot = lstart[BPB];
    for (int i = tid; i < ptot; i += 512) gsrc[b*ECAP + i] = lsrc[i];
    if (tid <= BPB){
        int mt = (tid < BPB) ? lcnt[tid] : 0;
        glh[b*64 + tid] = (lstart[tid] & 0xFFFF) | (mt << 16);
    }

    int lane = tid & 63, wid = tid >> 6;
    int q  = lane >> 4;
    int c4 = lane & 15;

    for (int nl = wid; nl < BPB; nl += 8){
        int node = nodeBase + nl;
        int s0 = lstart[nl];
        int m4 = lstart[nl+1] - s0;
        int mt = lcnt[nl];

        float a0=0.f, a1f=0.f, a2=0.f, a3=0.f;
        int j = 0;
        for (; j + 16 <= m4; j += 16){
            int sa = lsrc[s0 + j + q];
            int sb = lsrc[s0 + j + 4 + q];
            int sc = lsrc[s0 + j + 8 + q];
            int sd = lsrc[s0 + j + 12 + q];
            uint2 va = *(const uint2*)(hb + ((size_t)sa<<6) + (c4<<2));
            uint2 vb = *(const uint2*)(hb + ((size_t)sb<<6) + (c4<<2));
            uint2 vc = *(const uint2*)(hb + ((size_t)sc<<6) + (c4<<2));
            uint2 vd = *(const uint2*)(hb + ((size_t)sd<<6) + (c4<<2));
            a0  += __uint_as_float((va.x & 0xffffu) << 16) + __uint_as_float((vb.x & 0xffffu) << 16)
                 + __uint_as_float((vc.x & 0xffffu) << 16) + __uint_as_float((vd.x & 0xffffu) << 16);
            a1f += __uint_as_float(va.x & 0xffff0000u) + __uint_as_float(vb.x & 0xffff0000u)
                 + __uint_as_float(vc.x & 0xffff0000u) + __uint_as_float(vd.x & 0xffff0000u);
            a2  += __uint_as_float((va.y & 0xffffu) << 16) + __uint_as_float((vb.y & 0xffffu) << 16)
                 + __uint_as_float((vc.y & 0xffffu) << 16) + __uint_as_float((vd.y & 0xffffu) << 16);
            a3  += __uint_as_float(va.y & 0xffff0000u) + __uint_as_float(vb.y & 0xffff0000u)
                 + __uint_as_float(vc.y & 0xffff0000u) + __uint_as_float(vd.y & 0xffff0000u);
        }
        for (; j < m4; j += 4){
            int sa = lsrc[s0 + j + q];
            uint2 va = *(const uint2*)(hb + ((size_t)sa<<6) + (c4<<2));
            a0  += __uint_as_float((va.x & 0xffffu) << 16);
            a1f += __uint_as_float(va.x & 0xffff0000u);
            a2  += __uint_as_float((va.y & 0xffffu) << 16);
            a3  += __uint_as_float(va.y & 0xffff0000u);
        }
        a0  += __shfl_xor(a0, 16);  a0  += __shfl_xor(a0, 32);
        a1f += __shfl_xor(a1f, 16); a1f += __shfl_xor(a1f, 32);
        a2  += __shfl_xor(a2, 16);  a2  += __shfl_xor(a2, 32);
        a3  += __shfl_xor(a3, 16);  a3  += __shfl_xor(a3, 32);

        float dnv = rsqrtf((float)max(mt, 1));
        float snv = sn[node];
        float r0 = fmaxf(fmaf(a0,  dnv, b1s[(c4<<2)+0]), 0.f) * snv;
        float r1 = fmaxf(fmaf(a1f, dnv, b1s[(c4<<2)+1]), 0.f) * snv;
        float r2 = fmaxf(fmaf(a2,  dnv, b1s[(c4<<2)+2]), 0.f) * snv;
        float r3 = fmaxf(fmaf(a3,  dnv, b1s[(c4<<2)+3]), 0.f) * snv;
        if (q == 0){
            *(float4*)(&a1s[nl][c4<<2]) = make_float4(r0, r1, r2, r3);
        }
    }
    __syncthreads();

    for (int i = tid; i < BPB*10; i += 512){
        int nl = i / 10;
        int c  = i - nl*10;
        int node = nodeBase + nl;
        if (node < N){
            const float4* ap = (const float4*)(&a1s[nl][0]);
            const float4* wp = (const float4*)(&w2t[c][0]);
            float acc = 0.f;
            #pragma unroll
            for (int p=0;p<16;p++){
                float4 a = ap[p]; float4 w = wp[p];
                acc = fmaf(a.x, w.x, fmaf(a.y, w.y, fmaf(a.z, w.z, fmaf(a.w, w.w, acc))));
            }
            h2[(size_t)node*16 + c] = acc;
        }
    }
}

// ---------------- k_pool2 ----------------
__global__ __launch_bounds__(256) void k_pool2(const int* __restrict__ gsrc, const int* __restrict__ glh,
                                               const float* __restrict__ h2, const int* __restrict__ n2g,
                                               float* __restrict__ pooled, int N){
    __shared__ float accS[NG*10];
    int tid = threadIdx.x;
    for (int i=tid; i<NG*10; i+=256) accS[i] = 0.f;
    __syncthreads();
    int b = blockIdx.x;
    int nodeBase = b*BPB;
    int lane = tid & 63, wid = tid >> 6;
    int e6 = lane/10, c = lane - e6*10;
    bool active = (lane < 60);

    for (int nl = wid; nl < BPB; nl += 4){
        int node = nodeBase + nl;
        int cur = glh[b*64 + nl];
        int nxt = glh[b*64 + nl + 1];
        int base = b*ECAP + (cur & 0xFFFF);
        int m4   = (nxt & 0xFFFF) - (cur & 0xFFFF);
        int mt   = cur >> 16;
        float acc = 0.f;
        for (int j = 0; j < m4; j += 6){
            int idx = j + e6;
            int idxc = (idx < m4) ? idx : (m4-1);
            int srcn = gsrc[base + idxc];
            float v = h2[(size_t)srcn*16 + c];
            if (active && idx < m4) acc += v;
        }
        float t0 = __shfl(acc, lane+30); if (lane < 30) acc += t0;
        float t1 = __shfl(acc, lane+10);
        float t2 = __shfl(acc, lane+20);
        if (lane < 10){
            acc += t1 + t2;
            float dnv = rsqrtf((float)max(mt, 1));
            int g = n2g[node];
            atomicAdd(&accS[g*10 + lane], dnv*acc);
        }
    }
    __syncthreads();
    int g0 = n2g[nodeBase], g1 = n2g[nodeBase + BPB - 1];
    int lo = g0*10, hi = g1*10 + 10;
    for (int i = lo + tid; i < hi; i += 256)
        atomicAdd(&pooled[i], accS[i]);
}

// ---------------- final ----------------
__global__ void k_out(const float* __restrict__ pooled, const int* __restrict__ gstart,
                      const float* __restrict__ b2, float* __restrict__ out){
    int i = blockIdx.x*blockDim.x + threadIdx.x;
    if (i < NG*10){
        int g = i/10, c = i - g*10;
        float cnt = (float)max(gstart[g+1] - gstart[g], 1);
        out[i] = pooled[i]/cnt + b2[c];
    }
}

extern "C" void kernel_launch(void* const* d_in, const int* in_sizes, int n_in,
                              void* d_out, int out_size, void* d_ws, size_t ws_size,
                              hipStream_t stream) {
    const float* x    = (const float*)d_in[0];
    const int*   esrc = (const int*)d_in[1];
    const int*   edst = (const int*)d_in[2];
    const int*   n2g  = (const int*)d_in[3];
    const float* W1   = (const float*)d_in[5];
    const float* b1   = (const float*)d_in[6];
    const float* W2   = (const float*)d_in[7];
    const float* b2   = (const float*)d_in[8];
    float* out = (float*)d_out;
    int N = in_sizes[3];
    int E = in_sizes[1];

    char* ws = (char*)d_ws;
    size_t off = 0;
    auto alloc = [&](size_t bytes) -> void* {
        void* p = ws + off;
        off = (off + bytes + 255) & ~(size_t)255;
        return p;
    };
    float* pooled  = (float*)alloc(NG*10*4);
    int*   cntD    = (int*)alloc((size_t)GPART*NBUK2*4);
    int*   cntS    = (int*)alloc((size_t)GPART*NBUK2*4);
    int*   sliceD  = (int*)alloc((size_t)NSLICE*NBUK2*4);
    int*   sliceS  = (int*)alloc((size_t)NSLICE*NBUK2*4);
    int*   bstartD = (int*)alloc((NBUK+1)*4);
    int*   bstartS = (int*)alloc((NBUK+1)*4);
    int*   pairs   = (int*)alloc((size_t)E*4);
    unsigned char* srcb = (unsigned char*)alloc((size_t)E);
    int*   gsrc    = (int*)alloc((size_t)NBUK*ECAP*4);
    int*   glh     = (int*)alloc((size_t)NBUK*64*4);
    float* sn      = (float*)alloc((size_t)N*4);
    int*   gstart  = (int*)alloc((size_t)(NG+1)*4);
    short* Wb      = (short*)alloc((size_t)512*64*2);
    unsigned short* hb = (unsigned short*)alloc((size_t)(N+1)*64*2);
    float* h2      = (float*)alloc((size_t)(N+1)*16*4);

    k_start<<<dim3(GPART+PREPB+ZEROB+GSTB), dim3(256), 0, stream>>>(
        esrc, edst, cntD, cntS, E, W1, Wb, pooled, hb, h2, n2g, gstart, N);

    void* margs[] = {(void*)&cntD, (void*)&cntS, (void*)&sliceD, (void*)&sliceS,
                     (void*)&bstartD, (void*)&bstartS, (void*)&esrc, (void*)&edst,
                     (void*)&pairs, (void*)&srcb, (void*)&sn, (void*)&E, (void*)&N};
    (void)hipLaunchCooperativeKernel((void*)k_mid, dim3(GPART), dim3(256), margs, 0, stream);

    k_gemm1<<<dim3((N+127)/128), dim3(256), 0, stream>>>(x, Wb, sn, hb, N);

    k_agg<<<dim3(NBUK), dim3(512), 0, stream>>>(pairs, bstartD, hb, sn, b1, W2, h2, gsrc, glh, N);
    k_pool2<<<dim3(NBUK), dim3(256), 0, stream>>>(gsrc, glh, h2, n2g, pooled, N);
    k_out<<<dim3(3), dim3(256), 0, stream>>>(pooled, gstart, b2, out);
}

// Round 18
// 240.049 us; speedup vs baseline: 1.4687x; 1.4687x over previous
//
#include <hip/hip_runtime.h>

#define NN 100000
#define NE 1600000
#define NG 64
#define BPB  50
#define NBUK 2000
#define NBUK2 2048
#define ECAP 1152
#define GPART 256
#define NSLICE 8
#define SLB (GPART/NSLICE)
#define PREPB 128
#define ZEROB 3
#define GSTB ((NN+255)/256)

using bf16x8 = __attribute__((ext_vector_type(8))) short;
using f32x4  = __attribute__((ext_vector_type(4))) float;

__device__ inline unsigned short f2bf(float f){
    union { float f; unsigned u; } v; v.f = f;
    unsigned r = (v.u + 0x7FFFu + ((v.u >> 16) & 1u)) >> 16;
    return (unsigned short)r;
}

__device__ inline bf16x8 cvt8(f32x4 a, f32x4 b){
    union { unsigned u[4]; bf16x8 v; } r;
    asm("v_cvt_pk_bf16_f32 %0, %1, %2" : "=v"(r.u[0]) : "v"(a[0]), "v"(a[1]));
    asm("v_cvt_pk_bf16_f32 %0, %1, %2" : "=v"(r.u[1]) : "v"(a[2]), "v"(a[3]));
    asm("v_cvt_pk_bf16_f32 %0, %1, %2" : "=v"(r.u[2]) : "v"(b[0]), "v"(b[1]));
    asm("v_cvt_pk_bf16_f32 %0, %1, %2" : "=v"(r.u[3]) : "v"(b[2]), "v"(b[3]));
    return r.v;
}

// ---------------- k_start: count (int4) + prepw + zero + gstart ----------------
__global__ __launch_bounds__(256) void k_start(const int* __restrict__ src, const int* __restrict__ dst,
                                               int* __restrict__ cntD, int* __restrict__ cntS, int E,
                                               const float* __restrict__ W1, short* __restrict__ Wb,
                                               float* __restrict__ pooled,
                                               unsigned short* __restrict__ hb, float* __restrict__ h2,
                                               const int* __restrict__ n2g, int* __restrict__ gstart, int N){
    __shared__ int hD[NBUK2], hS[NBUK2];
    int bid = blockIdx.x;
    int tid = threadIdx.x;
    if (bid < GPART){
        for (int i=tid; i<NBUK2; i+=256){ hD[i]=0; hS[i]=0; }
        __syncthreads();
        int EV = E >> 2;
        int chunkV = (EV + GPART - 1)/GPART;
        int sV = bid*chunkV, eV = min(EV, sV+chunkV);
        for (int v = sV + tid; v < eV; v += 256){
            int4 s4 = ((const int4*)src)[v];
            int4 d4 = ((const int4*)dst)[v];
            atomicAdd(&hS[s4.x/BPB], 1); atomicAdd(&hS[s4.y/BPB], 1);
            atomicAdd(&hS[s4.z/BPB], 1); atomicAdd(&hS[s4.w/BPB], 1);
            atomicAdd(&hD[d4.x/BPB], 1); atomicAdd(&hD[d4.y/BPB], 1);
            atomicAdd(&hD[d4.z/BPB], 1); atomicAdd(&hD[d4.w/BPB], 1);
        }
        __syncthreads();
        for (int i=tid; i<NBUK2; i+=256){
            cntD[bid*NBUK2 + i] = hD[i];
            cntS[bid*NBUK2 + i] = hS[i];
        }
    } else if (bid < GPART+PREPB){
        int i = (bid-GPART)*256 + tid;
        if (i < 512*64){
            int k = i >> 6, c = i & 63;
            int g = k >> 5, r = k & 31, s = r >> 3, j = r & 7;
            Wb[(((g*4+s)*64 + c) << 3) + j] = (short)f2bf(W1[i]);
        }
    } else if (bid < GPART+PREPB+ZEROB){
        int i = (bid-GPART-PREPB)*256 + tid;
        if (i < NG*10) pooled[i] = 0.f;
        else if (i < NG*10 + 64) hb[(size_t)N*64 + (i - NG*10)] = 0;
        else if (i < NG*10 + 64 + 16) h2[(size_t)N*16 + (i - NG*10 - 64)] = 0.f;
    } else {
        int n = (bid-GPART-PREPB-ZEROB)*256 + tid;
        if (n < N){
            int g  = n2g[n];
            int gp = (n == 0) ? -1 : n2g[n-1];
            if (gp != g){
                for (int gg = gp+1; gg <= g; ++gg) gstart[gg] = n;
            }
            if (n == N-1){
                for (int gg = g+1; gg <= NG; ++gg) gstart[gg] = N;
            }
        }
    }
}

// ---------------- scan Ca ----------------
__global__ __launch_bounds__(256) void k_scanCa(const int* __restrict__ cntD, const int* __restrict__ cntS,
                                                int* __restrict__ sliceD, int* __restrict__ sliceS){
    int id = blockIdx.x*256 + threadIdx.x;
    int t = id & (NBUK2-1);
    int s = id >> 11;
    int b0 = s*SLB;
    int sD=0, sS=0;
    for (int b=b0; b<b0+SLB; b++){ sD += cntD[b*NBUK2+t]; sS += cntS[b*NBUK2+t]; }
    sliceD[s*NBUK2+t] = sD;
    sliceS[s*NBUK2+t] = sS;
}

// ---------------- scan B ----------------
__global__ __launch_bounds__(1024) void k_scanB(const int* __restrict__ sliceD, const int* __restrict__ sliceS,
                                                int* __restrict__ bstartD, int* __restrict__ bstartS){
    __shared__ int sd[1024];
    int t = threadIdx.x;
    {
        int v0=0, v1=0;
        #pragma unroll
        for (int s=0;s<NSLICE;s++){ v0 += sliceD[s*NBUK2 + 2*t]; v1 += sliceD[s*NBUK2 + 2*t+1]; }
        sd[t] = v0+v1; __syncthreads();
        for (int off=1; off<1024; off<<=1){
            int tv = (t >= off) ? sd[t-off] : 0;
            __syncthreads();
            sd[t] += tv;
            __syncthreads();
        }
        int excl = sd[t] - v0 - v1;
        if (2*t   <= NBUK) bstartD[2*t]   = excl;
        if (2*t+1 <= NBUK) bstartD[2*t+1] = excl + v0;
        __syncthreads();
    }
    {
        int v0=0, v1=0;
        #pragma unroll
        for (int s=0;s<NSLICE;s++){ v0 += sliceS[s*NBUK2 + 2*t]; v1 += sliceS[s*NBUK2 + 2*t+1]; }
        sd[t] = v0+v1; __syncthreads();
        for (int off=1; off<1024; off<<=1){
            int tv = (t >= off) ? sd[t-off] : 0;
            __syncthreads();
            sd[t] += tv;
            __syncthreads();
        }
        int excl = sd[t] - v0 - v1;
        if (2*t   <= NBUK) bstartS[2*t]   = excl;
        if (2*t+1 <= NBUK) bstartS[2*t+1] = excl + v0;
    }
}

// ---------------- scan Cb ----------------
__global__ __launch_bounds__(256) void k_scanCb(int* __restrict__ cntD, int* __restrict__ cntS,
                                                const int* __restrict__ sliceD, const int* __restrict__ sliceS,
                                                const int* __restrict__ bstartD, const int* __restrict__ bstartS){
    int id = blockIdx.x*256 + threadIdx.x;
    int t = id & (NBUK2-1);
    int s = id >> 11;
    if (t >= NBUK) return;
    int rD = bstartD[t], rS = bstartS[t];
    for (int sp=0; sp<s; sp++){ rD += sliceD[sp*NBUK2+t]; rS += sliceS[sp*NBUK2+t]; }
    int b0 = s*SLB;
    for (int b=b0; b<b0+SLB; b++){
        int idx = b*NBUK2 + t;
        int o = cntD[idx]; cntD[idx] = rD; rD += o;
        o = cntS[idx];     cntS[idx] = rS; rS += o;
    }
}

// ---------------- scatter (int4 edge loads) ----------------
__global__ __launch_bounds__(256) void k_scatter(const int* __restrict__ src, const int* __restrict__ dst,
                                                 const int* __restrict__ cntD, const int* __restrict__ cntS,
                                                 int* __restrict__ pairs, unsigned char* __restrict__ srcb, int E){
    __shared__ unsigned oD[NBUK2], oS[NBUK2];
    for (int i=threadIdx.x; i<NBUK2; i+=256){
        oD[i] = (unsigned)cntD[blockIdx.x*NBUK2 + i];
        oS[i] = (unsigned)cntS[blockIdx.x*NBUK2 + i];
    }
    __syncthreads();
    int EV = E >> 2;
    int chunkV = (EV + GPART - 1)/GPART;
    int sV = blockIdx.x*chunkV, eV = min(EV, sV+chunkV);
    for (int v = sV + threadIdx.x; v < eV; v += 256){
        int4 s4 = ((const int4*)src)[v];
        int4 d4 = ((const int4*)dst)[v];
        #pragma unroll
        for (int k=0;k<4;k++){
            int s = (k==0)?s4.x:(k==1)?s4.y:(k==2)?s4.z:s4.w;
            int d = (k==0)?d4.x:(k==1)?d4.y:(k==2)?d4.z:d4.w;
            int bk = d/BPB;
            unsigned pD = atomicAdd(&oD[bk], 1u);
            pairs[pD] = (s << 6) | (d - bk*BPB);
            int sb = s/BPB;
            unsigned pS = atomicAdd(&oS[sb], 1u);
            srcb[pS] = (unsigned char)(s - sb*BPB);
        }
    }
}

// ---------------- out-degree per node -> sn ----------------
__global__ __launch_bounds__(256) void k_outdeg(const unsigned char* __restrict__ srcb,
                                                const int* __restrict__ bstartS,
                                                float* __restrict__ sn, int N){
    __shared__ int c[BPB];
    int b = blockIdx.x;
    if (threadIdx.x < BPB) c[threadIdx.x] = 0;
    __syncthreads();
    int s0 = bstartS[b], s1 = bstartS[b+1];
    for (int i = s0 + threadIdx.x; i < s1; i += 256)
        atomicAdd(&c[srcb[i]], 1);
    __syncthreads();
    int node = b*BPB + threadIdx.x;
    if (threadIdx.x < BPB && node < N)
        sn[node] = rsqrtf((float)max(c[threadIdx.x], 1));
}

// ---------------- GEMM1 (MFMA bf16): hb = (x @ W1) * sn; 32 rows/wave; NT x loads ----------------
__global__ __launch_bounds__(256) void k_gemm1(const float* __restrict__ x, const short* __restrict__ Wb,
                                               const float* __restrict__ sn, unsigned short* __restrict__ hb, int N){
    const int lane = threadIdx.x & 63;
    const int wid  = threadIdx.x >> 6;
    const int rowBase = blockIdx.x*128 + wid*32;
    const int mrow = lane & 15;
    const int s    = lane >> 4;

    int rowA = rowBase + mrow;
    int rowB = rowBase + 16 + mrow;
    int rcA = (rowA < N) ? rowA : (N-1);
    int rcB = (rowB < N) ? rowB : (N-1);

    const f32x4* __restrict__ xv = (const f32x4*)x;
    const bf16x8* __restrict__ wv = (const bf16x8*)Wb;
    const f32x4* xrA = xv + (size_t)rcA*128 + s*2;
    const f32x4* xrB = xv + (size_t)rcB*128 + s*2;

    f32x4 accA0 = {0,0,0,0}, accA1 = {0,0,0,0}, accA2 = {0,0,0,0}, accA3 = {0,0,0,0};
    f32x4 accB0 = {0,0,0,0}, accB1 = {0,0,0,0}, accB2 = {0,0,0,0}, accB3 = {0,0,0,0};

    #pragma unroll 2
    for (int g=0; g<16; g++){
        f32x4 a0 = __builtin_nontemporal_load(xrA + g*8 + 0);
        f32x4 a1 = __builtin_nontemporal_load(xrA + g*8 + 1);
        f32x4 c0 = __builtin_nontemporal_load(xrB + g*8 + 0);
        f32x4 c1 = __builtin_nontemporal_load(xrB + g*8 + 1);
        bf16x8 afA = cvt8(a0, a1);
        bf16x8 afB = cvt8(c0, c1);
        int bbase = (g*4 + s)*64 + mrow;
        bf16x8 b0 = wv[bbase     ];
        bf16x8 b1 = wv[bbase + 16];
        bf16x8 b2 = wv[bbase + 32];
        bf16x8 b3 = wv[bbase + 48];
        accA0 = __builtin_amdgcn_mfma_f32_16x16x32_bf16(afA, b0, accA0, 0, 0, 0);
        accA1 = __builtin_amdgcn_mfma_f32_16x16x32_bf16(afA, b1, accA1, 0, 0, 0);
        accA2 = __builtin_amdgcn_mfma_f32_16x16x32_bf16(afA, b2, accA2, 0, 0, 0);
        accA3 = __builtin_amdgcn_mfma_f32_16x16x32_bf16(afA, b3, accA3, 0, 0, 0);
        accB0 = __builtin_amdgcn_mfma_f32_16x16x32_bf16(afB, b0, accB0, 0, 0, 0);
        accB1 = __builtin_amdgcn_mfma_f32_16x16x32_bf16(afB, b1, accB1, 0, 0, 0);
        accB2 = __builtin_amdgcn_mfma_f32_16x16x32_bf16(afB, b2, accB2, 0, 0, 0);
        accB3 = __builtin_amdgcn_mfma_f32_16x16x32_bf16(afB, b3, accB3, 0, 0, 0);
    }

    #pragma unroll
    for (int q=0; q<4; q++){
        int rr = rowBase + s*4 + q;
        if (rr < N){
            float scale = sn[rr];
            unsigned short* hp = hb + ((size_t)rr<<6) + mrow;
            hp[ 0] = f2bf(accA0[q] * scale);
            hp[16] = f2bf(accA1[q] * scale);
            hp[32] = f2bf(accA2[q] * scale);
            hp[48] = f2bf(accA3[q] * scale);
        }
        int r2 = rowBase + 16 + s*4 + q;
        if (r2 < N){
            float scale = sn[r2];
            unsigned short* hp = hb + ((size_t)r2<<6) + mrow;
            hp[ 0] = f2bf(accB0[q] * scale);
            hp[16] = f2bf(accB1[q] * scale);
            hp[32] = f2bf(accB2[q] * scale);
            hp[48] = f2bf(accB3[q] * scale);
        }
    }
}

// ---------------- phase D: padded CSR-in-LDS gather (predicate-free) + LDS GEMM2 ----------------
__global__ __launch_bounds__(256) void k_agg(const int* __restrict__ pairs, const int* __restrict__ bstartD,
                                             const unsigned short* __restrict__ hb,
                                             const float* __restrict__ sn, const float* __restrict__ b1,
                                             const float* __restrict__ W2,
                                             float* __restrict__ h2, int* __restrict__ gsrc,
                                             int* __restrict__ glh, int N){
    __shared__ int lsrc[ECAP];
    __shared__ int lcnt[BPB];
    __shared__ int lstart[BPB+1];
    __shared__ unsigned lofs[BPB];
    __shared__ __align__(16) float w2t[10][64];
    __shared__ float b1s[64];
    __shared__ __align__(16) float a1s[BPB][68];
    int tid = threadIdx.x;
    if (tid < BPB) lcnt[tid] = 0;
    if (tid < 64)  b1s[tid] = b1[tid];
    for (int i=tid; i<ECAP; i+=256) lsrc[i] = N;
    for (int i=tid; i<640; i+=256){ int c = i>>6, k = i&63; w2t[c][k] = W2[k*10 + c]; }
    __syncthreads();

    int b = blockIdx.x;
    int nodeBase = b*BPB;
    int eb = bstartD[b], ee = bstartD[b+1];
    int ne = ee - eb;

    for (int i = tid; i < ne; i += 256){
        int pr = pairs[eb + i];
        atomicAdd(&lcnt[pr & 63], 1);
    }
    __syncthreads();
    if (tid < 64){
        int mt = (tid < BPB) ? lcnt[tid] : 0;
        int v = (mt + 3) & ~3;
        int sI = v;
        for (int off=1; off<64; off<<=1){
            int t = __shfl_up(sI, off);
            if (tid >= off) sI += t;
        }
        if (tid < BPB){
            lstart[tid] = sI - v;
            lofs[tid]   = (unsigned)(sI - v);
            if (tid == BPB-1) lstart[BPB] = sI;
        }
    }
    __syncthreads();
    for (int i = tid; i < ne; i += 256){
        int pr = pairs[eb + i];
        unsigned pos = atomicAdd(&lofs[pr & 63], 1u);
        lsrc[pos < ECAP ? pos : ECAP-1] = pr >> 6;
    }
    __syncthreads();

    int ptot = lstart[BPB];
    for (int i = tid; i < ptot; i += 256) gsrc[b*ECAP + i] = lsrc[i];
    if (tid <= BPB){
        int mt = (tid < BPB) ? lcnt[tid] : 0;
        glh[b*64 + tid] = (lstart[tid] & 0xFFFF) | (mt << 16);
    }

    int lane = tid & 63, wid = tid >> 6;
    int q  = lane >> 4;
    int c4 = lane & 15;

    for (int nl = wid; nl < BPB; nl += 4){
        int node = nodeBase + nl;
        int s0 = lstart[nl];
        int m4 = lstart[nl+1] - s0;
        int mt = lcnt[nl];

        float a0=0.f, a1f=0.f, a2=0.f, a3=0.f;
        int j = 0;
        for (; j + 16 <= m4; j += 16){
            int sa = lsrc[s0 + j + q];
            int sb = lsrc[s0 + j + 4 + q];
            int sc = lsrc[s0 + j + 8 + q];
            int sd = lsrc[s0 + j + 12 + q];
            uint2 va = *(const uint2*)(hb + ((size_t)sa<<6) + (c4<<2));
            uint2 vb = *(const uint2*)(hb + ((size_t)sb<<6) + (c4<<2));
            uint2 vc = *(const uint2*)(hb + ((size_t)sc<<6) + (c4<<2));
            uint2 vd = *(const uint2*)(hb + ((size_t)sd<<6) + (c4<<2));
            a0  += __uint_as_float((va.x & 0xffffu) << 16) + __uint_as_float((vb.x & 0xffffu) << 16)
                 + __uint_as_float((vc.x & 0xffffu) << 16) + __uint_as_float((vd.x & 0xffffu) << 16);
            a1f += __uint_as_float(va.x & 0xffff0000u) + __uint_as_float(vb.x & 0xffff0000u)
                 + __uint_as_float(vc.x & 0xffff0000u) + __uint_as_float(vd.x & 0xffff0000u);
            a2  += __uint_as_float((va.y & 0xffffu) << 16) + __uint_as_float((vb.y & 0xffffu) << 16)
                 + __uint_as_float((vc.y & 0xffffu) << 16) + __uint_as_float((vd.y & 0xffffu) << 16);
            a3  += __uint_as_float(va.y & 0xffff0000u) + __uint_as_float(vb.y & 0xffff0000u)
                 + __uint_as_float(vc.y & 0xffff0000u) + __uint_as_float(vd.y & 0xffff0000u);
        }
        for (; j < m4; j += 4){
            int sa = lsrc[s0 + j + q];
            uint2 va = *(const uint2*)(hb + ((size_t)sa<<6) + (c4<<2));
            a0  += __uint_as_float((va.x & 0xffffu) << 16);
            a1f += __uint_as_float(va.x & 0xffff0000u);
            a2  += __uint_as_float((va.y & 0xffffu) << 16);
            a3  += __uint_as_float(va.y & 0xffff0000u);
        }
        a0  += __shfl_xor(a0, 16);  a0  += __shfl_xor(a0, 32);
        a1f += __shfl_xor(a1f, 16); a1f += __shfl_xor(a1f, 32);
        a2  += __shfl_xor(a2, 16);  a2  += __shfl_xor(a2, 32);
        a3  += __shfl_xor(a3, 16);  a3  += __shfl_xor(a3, 32);

        float dnv = rsqrtf((float)max(mt, 1));
        float snv = sn[node];
        float r0 = fmaxf(fmaf(a0,  dnv, b1s[(c4<<2)+0]), 0.f) * snv;
        float r1 = fmaxf(fmaf(a1f, dnv, b1s[(c4<<2)+1]), 0.f) * snv;
        float r2 = fmaxf(fmaf(a2,  dnv, b1s[(c4<<2)+2]), 0.f) * snv;
        float r3 = fmaxf(fmaf(a3,  dnv, b1s[(c4<<2)+3]), 0.f) * snv;
        if (q == 0){
            *(float4*)(&a1s[nl][c4<<2]) = make_float4(r0, r1, r2, r3);
        }
    }
    __syncthreads();

    for (int i = tid; i < BPB*10; i += 256){
        int nl = i / 10;
        int c  = i - nl*10;
        int node = nodeBase + nl;
        if (node < N){
            const float4* ap = (const float4*)(&a1s[nl][0]);
            const float4* wp = (const float4*)(&w2t[c][0]);
            float acc = 0.f;
            #pragma unroll
            for (int p=0;p<16;p++){
                float4 a = ap[p]; float4 w = wp[p];
                acc = fmaf(a.x, w.x, fmaf(a.y, w.y, fmaf(a.z, w.z, fmaf(a.w, w.w, acc))));
            }
            h2[(size_t)node*16 + c] = acc;
        }
    }
}

// ---------------- k_pool2 ----------------
__global__ __launch_bounds__(256) void k_pool2(const int* __restrict__ gsrc, const int* __restrict__ glh,
                                               const float* __restrict__ h2, const int* __restrict__ n2g,
                                               float* __restrict__ pooled, int N){
    __shared__ float accS[NG*10];
    int tid = threadIdx.x;
    for (int i=tid; i<NG*10; i+=256) accS[i] = 0.f;
    __syncthreads();
    int b = blockIdx.x;
    int nodeBase = b*BPB;
    int lane = tid & 63, wid = tid >> 6;
    int e6 = lane/10, c = lane - e6*10;
    bool active = (lane < 60);

    for (int nl = wid; nl < BPB; nl += 4){
        int node = nodeBase + nl;
        int cur = glh[b*64 + nl];
        int nxt = glh[b*64 + nl + 1];
        int base = b*ECAP + (cur & 0xFFFF);
        int m4   = (nxt & 0xFFFF) - (cur & 0xFFFF);
        int mt   = cur >> 16;
        float acc = 0.f;
        for (int j = 0; j < m4; j += 6){
            int idx = j + e6;
            int idxc = (idx < m4) ? idx : (m4-1);
            int srcn = gsrc[base + idxc];
            float v = h2[(size_t)srcn*16 + c];
            if (active && idx < m4) acc += v;
        }
        float t0 = __shfl(acc, lane+30); if (lane < 30) acc += t0;
        float t1 = __shfl(acc, lane+10);
        float t2 = __shfl(acc, lane+20);
        if (lane < 10){
            acc += t1 + t2;
            float dnv = rsqrtf((float)max(mt, 1));
            int g = n2g[node];
            atomicAdd(&accS[g*10 + lane], dnv*acc);
        }
    }
    __syncthreads();
    int g0 = n2g[nodeBase], g1 = n2g[nodeBase + BPB - 1];
    int lo = g0*10, hi = g1*10 + 10;
    for (int i = lo + tid; i < hi; i += 256)
        atomicAdd(&pooled[i], accS[i]);
}

// ---------------- final ----------------
__global__ void k_out(const float* __restrict__ pooled, const int* __restrict__ gstart,
                      const float* __restrict__ b2, float* __restrict__ out){
    int i = blockIdx.x*blockDim.x + threadIdx.x;
    if (i < NG*10){
        int g = i/10, c = i - g*10;
        float cnt = (float)max(gstart[g+1] - gstart[g], 1);
        out[i] = pooled[i]/cnt + b2[c];
    }
}

extern "C" void kernel_launch(void* const* d_in, const int* in_sizes, int n_in,
                              void* d_out, int out_size, void* d_ws, size_t ws_size,
                              hipStream_t stream) {
    const float* x    = (const float*)d_in[0];
    const int*   esrc = (const int*)d_in[1];
    const int*   edst = (const int*)d_in[2];
    const int*   n2g  = (const int*)d_in[3];
    const float* W1   = (const float*)d_in[5];
    const float* b1   = (const float*)d_in[6];
    const float* W2   = (const float*)d_in[7];
    const float* b2   = (const float*)d_in[8];
    float* out = (float*)d_out;
    const int N = in_sizes[3];
    const int E = in_sizes[1];

    char* ws = (char*)d_ws;
    size_t off = 0;
    auto alloc = [&](size_t bytes) -> void* {
        void* p = ws + off;
        off = (off + bytes + 255) & ~(size_t)255;
        return p;
    };
    float* pooled  = (float*)alloc(NG*10*4);
    int*   cntD    = (int*)alloc((size_t)GPART*NBUK2*4);
    int*   cntS    = (int*)alloc((size_t)GPART*NBUK2*4);
    int*   sliceD  = (int*)alloc((size_t)NSLICE*NBUK2*4);
    int*   sliceS  = (int*)alloc((size_t)NSLICE*NBUK2*4);
    int*   bstartD = (int*)alloc((NBUK+1)*4);
    int*   bstartS = (int*)alloc((NBUK+1)*4);
    int*   pairs   = (int*)alloc((size_t)E*4);
    unsigned char* srcb = (unsigned char*)alloc((size_t)E);
    int*   gsrc    = (int*)alloc((size_t)NBUK*ECAP*4);
    int*   glh     = (int*)alloc((size_t)NBUK*64*4);
    float* sn      = (float*)alloc((size_t)N*4);
    int*   gstart  = (int*)alloc((size_t)(NG+1)*4);
    short* Wb      = (short*)alloc((size_t)512*64*2);
    unsigned short* hb = (unsigned short*)alloc((size_t)(N+1)*64*2);
    float* h2      = (float*)alloc((size_t)(N+1)*16*4);

    k_start<<<dim3(GPART+PREPB+ZEROB+GSTB), dim3(256), 0, stream>>>(
        esrc, edst, cntD, cntS, E, W1, Wb, pooled, hb, h2, n2g, gstart, N);
    k_scanCa<<<dim3(64), dim3(256), 0, stream>>>(cntD, cntS, sliceD, sliceS);
    k_scanB<<<dim3(1), dim3(1024), 0, stream>>>(sliceD, sliceS, bstartD, bstartS);
    k_scanCb<<<dim3(64), dim3(256), 0, stream>>>(cntD, cntS, sliceD, sliceS, bstartD, bstartS);
    k_scatter<<<dim3(GPART), dim3(256), 0, stream>>>(esrc, edst, cntD, cntS, pairs, srcb, E);
    k_outdeg<<<dim3(NBUK), dim3(256), 0, stream>>>(srcb, bstartS, sn, N);

    k_gemm1<<<dim3((N+127)/128), dim3(256), 0, stream>>>(x, Wb, sn, hb, N);

    k_agg<<<dim3(NBUK), dim3(256), 0, stream>>>(pairs, bstartD, hb, sn, b1, W2, h2, gsrc, glh, N);
    k_pool2<<<dim3(NBUK), dim3(256), 0, stream>>>(gsrc, glh, h2, n2g, pooled, N);
    k_out<<<dim3(3), dim3(256), 0, stream>>>(pooled, gstart, b2, out);
}

// Round 19
// 223.699 us; speedup vs baseline: 1.5761x; 1.0731x over previous
//
#include <hip/hip_runtime.h>

#define NN 100000
#define NE 1600000
#define NG 64
#define BPB  50
#define NBUK 2000
#define NBUK2 2048
#define ECAP 1152
#define GPART 256
#define NSLICE 8
#define SLB (GPART/NSLICE)
#define PREPB 128
#define ZEROB 3
#define GSTB ((NN+255)/256)

using bf16x8 = __attribute__((ext_vector_type(8))) short;
using f32x4  = __attribute__((ext_vector_type(4))) float;

__device__ inline unsigned short f2bf(float f){
    union { float f; unsigned u; } v; v.f = f;
    unsigned r = (v.u + 0x7FFFu + ((v.u >> 16) & 1u)) >> 16;
    return (unsigned short)r;
}

__device__ inline bf16x8 cvt8(f32x4 a, f32x4 b){
    union { unsigned u[4]; bf16x8 v; } r;
    asm("v_cvt_pk_bf16_f32 %0, %1, %2" : "=v"(r.u[0]) : "v"(a[0]), "v"(a[1]));
    asm("v_cvt_pk_bf16_f32 %0, %1, %2" : "=v"(r.u[1]) : "v"(a[2]), "v"(a[3]));
    asm("v_cvt_pk_bf16_f32 %0, %1, %2" : "=v"(r.u[2]) : "v"(b[0]), "v"(b[1]));
    asm("v_cvt_pk_bf16_f32 %0, %1, %2" : "=v"(r.u[3]) : "v"(b[2]), "v"(b[3]));
    return r.v;
}

// ---------------- k_start: count (int4) + prepw + zero + gstart ----------------
__global__ __launch_bounds__(256) void k_start(const int* __restrict__ src, const int* __restrict__ dst,
                                               int* __restrict__ cntD, int* __restrict__ cntS, int E,
                                               const float* __restrict__ W1, short* __restrict__ Wb,
                                               float* __restrict__ pooled,
                                               unsigned short* __restrict__ hb, float* __restrict__ h2,
                                               const int* __restrict__ n2g, int* __restrict__ gstart, int N){
    __shared__ int hD[NBUK2], hS[NBUK2];
    int bid = blockIdx.x;
    int tid = threadIdx.x;
    if (bid < GPART){
        for (int i=tid; i<NBUK2; i+=256){ hD[i]=0; hS[i]=0; }
        __syncthreads();
        int EV = E >> 2;
        int chunkV = (EV + GPART - 1)/GPART;
        int sV = bid*chunkV, eV = min(EV, sV+chunkV);
        for (int v = sV + tid; v < eV; v += 256){
            int4 s4 = ((const int4*)src)[v];
            int4 d4 = ((const int4*)dst)[v];
            atomicAdd(&hS[s4.x/BPB], 1); atomicAdd(&hS[s4.y/BPB], 1);
            atomicAdd(&hS[s4.z/BPB], 1); atomicAdd(&hS[s4.w/BPB], 1);
            atomicAdd(&hD[d4.x/BPB], 1); atomicAdd(&hD[d4.y/BPB], 1);
            atomicAdd(&hD[d4.z/BPB], 1); atomicAdd(&hD[d4.w/BPB], 1);
        }
        __syncthreads();
        for (int i=tid; i<NBUK2; i+=256){
            cntD[bid*NBUK2 + i] = hD[i];
            cntS[bid*NBUK2 + i] = hS[i];
        }
    } else if (bid < GPART+PREPB){
        int i = (bid-GPART)*256 + tid;
        if (i < 512*64){
            int k = i >> 6, c = i & 63;
            int g = k >> 5, r = k & 31, s = r >> 3, j = r & 7;
            Wb[(((g*4+s)*64 + c) << 3) + j] = (short)f2bf(W1[i]);
        }
    } else if (bid < GPART+PREPB+ZEROB){
        int i = (bid-GPART-PREPB)*256 + tid;
        if (i < NG*10) pooled[i] = 0.f;
        else if (i < NG*10 + 64) hb[(size_t)N*64 + (i - NG*10)] = 0;
        else if (i < NG*10 + 64 + 16) h2[(size_t)N*16 + (i - NG*10 - 64)] = 0.f;
    } else {
        int n = (bid-GPART-PREPB-ZEROB)*256 + tid;
        if (n < N){
            int g  = n2g[n];
            int gp = (n == 0) ? -1 : n2g[n-1];
            if (gp != g){
                for (int gg = gp+1; gg <= g; ++gg) gstart[gg] = n;
            }
            if (n == N-1){
                for (int gg = g+1; gg <= NG; ++gg) gstart[gg] = N;
            }
        }
    }
}

// ---------------- scan Ca ----------------
__global__ __launch_bounds__(256) void k_scanCa(const int* __restrict__ cntD, const int* __restrict__ cntS,
                                                int* __restrict__ sliceD, int* __restrict__ sliceS){
    int id = blockIdx.x*256 + threadIdx.x;
    int t = id & (NBUK2-1);
    int s = id >> 11;
    int b0 = s*SLB;
    int sD=0, sS=0;
    for (int b=b0; b<b0+SLB; b++){ sD += cntD[b*NBUK2+t]; sS += cntS[b*NBUK2+t]; }
    sliceD[s*NBUK2+t] = sD;
    sliceS[s*NBUK2+t] = sS;
}

// ---------------- scan B ----------------
__global__ __launch_bounds__(1024) void k_scanB(const int* __restrict__ sliceD, const int* __restrict__ sliceS,
                                                int* __restrict__ bstartD, int* __restrict__ bstartS){
    __shared__ int sd[1024];
    int t = threadIdx.x;
    {
        int v0=0, v1=0;
        #pragma unroll
        for (int s=0;s<NSLICE;s++){ v0 += sliceD[s*NBUK2 + 2*t]; v1 += sliceD[s*NBUK2 + 2*t+1]; }
        sd[t] = v0+v1; __syncthreads();
        for (int off=1; off<1024; off<<=1){
            int tv = (t >= off) ? sd[t-off] : 0;
            __syncthreads();
            sd[t] += tv;
            __syncthreads();
        }
        int excl = sd[t] - v0 - v1;
        if (2*t   <= NBUK) bstartD[2*t]   = excl;
        if (2*t+1 <= NBUK) bstartD[2*t+1] = excl + v0;
        __syncthreads();
    }
    {
        int v0=0, v1=0;
        #pragma unroll
        for (int s=0;s<NSLICE;s++){ v0 += sliceS[s*NBUK2 + 2*t]; v1 += sliceS[s*NBUK2 + 2*t+1]; }
        sd[t] = v0+v1; __syncthreads();
        for (int off=1; off<1024; off<<=1){
            int tv = (t >= off) ? sd[t-off] : 0;
            __syncthreads();
            sd[t] += tv;
            __syncthreads();
        }
        int excl = sd[t] - v0 - v1;
        if (2*t   <= NBUK) bstartS[2*t]   = excl;
        if (2*t+1 <= NBUK) bstartS[2*t+1] = excl + v0;
    }
}

// ---------------- scan Cb ----------------
__global__ __launch_bounds__(256) void k_scanCb(int* __restrict__ cntD, int* __restrict__ cntS,
                                                const int* __restrict__ sliceD, const int* __restrict__ sliceS,
                                                const int* __restrict__ bstartD, const int* __restrict__ bstartS){
    int id = blockIdx.x*256 + threadIdx.x;
    int t = id & (NBUK2-1);
    int s = id >> 11;
    if (t >= NBUK) return;
    int rD = bstartD[t], rS = bstartS[t];
    for (int sp=0; sp<s; sp++){ rD += sliceD[sp*NBUK2+t]; rS += sliceS[sp*NBUK2+t]; }
    int b0 = s*SLB;
    for (int b=b0; b<b0+SLB; b++){
        int idx = b*NBUK2 + t;
        int o = cntD[idx]; cntD[idx] = rD; rD += o;
        o = cntS[idx];     cntS[idx] = rS; rS += o;
    }
}

// ---------------- scatter (int4 edge loads) ----------------
__global__ __launch_bounds__(256) void k_scatter(const int* __restrict__ src, const int* __restrict__ dst,
                                                 const int* __restrict__ cntD, const int* __restrict__ cntS,
                                                 int* __restrict__ pairs, unsigned char* __restrict__ srcb, int E){
    __shared__ unsigned oD[NBUK2], oS[NBUK2];
    for (int i=threadIdx.x; i<NBUK2; i+=256){
        oD[i] = (unsigned)cntD[blockIdx.x*NBUK2 + i];
        oS[i] = (unsigned)cntS[blockIdx.x*NBUK2 + i];
    }
    __syncthreads();
    int EV = E >> 2;
    int chunkV = (EV + GPART - 1)/GPART;
    int sV = blockIdx.x*chunkV, eV = min(EV, sV+chunkV);
    for (int v = sV + threadIdx.x; v < eV; v += 256){
        int4 s4 = ((const int4*)src)[v];
        int4 d4 = ((const int4*)dst)[v];
        #pragma unroll
        for (int k=0;k<4;k++){
            int s = (k==0)?s4.x:(k==1)?s4.y:(k==2)?s4.z:s4.w;
            int d = (k==0)?d4.x:(k==1)?d4.y:(k==2)?d4.z:d4.w;
            int bk = d/BPB;
            unsigned pD = atomicAdd(&oD[bk], 1u);
            pairs[pD] = (s << 6) | (d - bk*BPB);
            int sb = s/BPB;
            unsigned pS = atomicAdd(&oS[sb], 1u);
            srcb[pS] = (unsigned char)(s - sb*BPB);
        }
    }
}

// ---------------- out-degree per node -> sn ----------------
__global__ __launch_bounds__(256) void k_outdeg(const unsigned char* __restrict__ srcb,
                                                const int* __restrict__ bstartS,
                                                float* __restrict__ sn, int N){
    __shared__ int c[BPB];
    int b = blockIdx.x;
    if (threadIdx.x < BPB) c[threadIdx.x] = 0;
    __syncthreads();
    int s0 = bstartS[b], s1 = bstartS[b+1];
    for (int i = s0 + threadIdx.x; i < s1; i += 256)
        atomicAdd(&c[srcb[i]], 1);
    __syncthreads();
    int node = b*BPB + threadIdx.x;
    if (threadIdx.x < BPB && node < N)
        sn[node] = rsqrtf((float)max(c[threadIdx.x], 1));
}

// ---------------- GEMM1 (MFMA bf16): hb = (x @ W1) * sn; 32 rows/wave ----------------
__global__ __launch_bounds__(256) void k_gemm1(const float* __restrict__ x, const short* __restrict__ Wb,
                                               const float* __restrict__ sn, unsigned short* __restrict__ hb, int N){
    const int lane = threadIdx.x & 63;
    const int wid  = threadIdx.x >> 6;
    const int rowBase = blockIdx.x*128 + wid*32;
    const int mrow = lane & 15;
    const int s    = lane >> 4;

    int rowA = rowBase + mrow;
    int rowB = rowBase + 16 + mrow;
    int rcA = (rowA < N) ? rowA : (N-1);
    int rcB = (rowB < N) ? rowB : (N-1);

    const f32x4* __restrict__ xv = (const f32x4*)x;
    const bf16x8* __restrict__ wv = (const bf16x8*)Wb;
    const f32x4* xrA = xv + (size_t)rcA*128 + s*2;
    const f32x4* xrB = xv + (size_t)rcB*128 + s*2;

    f32x4 accA0 = {0,0,0,0}, accA1 = {0,0,0,0}, accA2 = {0,0,0,0}, accA3 = {0,0,0,0};
    f32x4 accB0 = {0,0,0,0}, accB1 = {0,0,0,0}, accB2 = {0,0,0,0}, accB3 = {0,0,0,0};

    #pragma unroll 2
    for (int g=0; g<16; g++){
        f32x4 a0 = xrA[g*8 + 0];
        f32x4 a1 = xrA[g*8 + 1];
        f32x4 c0 = xrB[g*8 + 0];
        f32x4 c1 = xrB[g*8 + 1];
        bf16x8 afA = cvt8(a0, a1);
        bf16x8 afB = cvt8(c0, c1);
        int bbase = (g*4 + s)*64 + mrow;
        bf16x8 b0 = wv[bbase     ];
        bf16x8 b1 = wv[bbase + 16];
        bf16x8 b2 = wv[bbase + 32];
        bf16x8 b3 = wv[bbase + 48];
        accA0 = __builtin_amdgcn_mfma_f32_16x16x32_bf16(afA, b0, accA0, 0, 0, 0);
        accA1 = __builtin_amdgcn_mfma_f32_16x16x32_bf16(afA, b1, accA1, 0, 0, 0);
        accA2 = __builtin_amdgcn_mfma_f32_16x16x32_bf16(afA, b2, accA2, 0, 0, 0);
        accA3 = __builtin_amdgcn_mfma_f32_16x16x32_bf16(afA, b3, accA3, 0, 0, 0);
        accB0 = __builtin_amdgcn_mfma_f32_16x16x32_bf16(afB, b0, accB0, 0, 0, 0);
        accB1 = __builtin_amdgcn_mfma_f32_16x16x32_bf16(afB, b1, accB1, 0, 0, 0);
        accB2 = __builtin_amdgcn_mfma_f32_16x16x32_bf16(afB, b2, accB2, 0, 0, 0);
        accB3 = __builtin_amdgcn_mfma_f32_16x16x32_bf16(afB, b3, accB3, 0, 0, 0);
    }

    #pragma unroll
    for (int q=0; q<4; q++){
        int rr = rowBase + s*4 + q;
        if (rr < N){
            float scale = sn[rr];
            unsigned short* hp = hb + ((size_t)rr<<6) + mrow;
            hp[ 0] = f2bf(accA0[q] * scale);
            hp[16] = f2bf(accA1[q] * scale);
            hp[32] = f2bf(accA2[q] * scale);
            hp[48] = f2bf(accA3[q] * scale);
        }
        int r2 = rowBase + 16 + s*4 + q;
        if (r2 < N){
            float scale = sn[r2];
            unsigned short* hp = hb + ((size_t)r2<<6) + mrow;
            hp[ 0] = f2bf(accB0[q] * scale);
            hp[16] = f2bf(accB1[q] * scale);
            hp[32] = f2bf(accB2[q] * scale);
            hp[48] = f2bf(accB3[q] * scale);
        }
    }
}

// ---------------- phase D: padded CSR-in-LDS gather (predicate-free) + LDS GEMM2 ----------------
__global__ __launch_bounds__(256) void k_agg(const int* __restrict__ pairs, const int* __restrict__ bstartD,
                                             const unsigned short* __restrict__ hb,
                                             const float* __restrict__ sn, const float* __restrict__ b1,
                                             const float* __restrict__ W2,
                                             float* __restrict__ h2, int* __restrict__ gsrc,
                                             int* __restrict__ glh, int N){
    __shared__ int lsrc[ECAP];
    __shared__ int lcnt[BPB];
    __shared__ int lstart[BPB+1];
    __shared__ unsigned lofs[BPB];
    __shared__ __align__(16) float w2t[10][64];
    __shared__ float b1s[64];
    __shared__ __align__(16) float a1s[BPB][68];
    int tid = threadIdx.x;
    if (tid < BPB) lcnt[tid] = 0;
    if (tid < 64)  b1s[tid] = b1[tid];
    for (int i=tid; i<ECAP; i+=256) lsrc[i] = N;
    for (int i=tid; i<640; i+=256){ int c = i>>6, k = i&63; w2t[c][k] = W2[k*10 + c]; }
    __syncthreads();

    int b = blockIdx.x;
    int nodeBase = b*BPB;
    int eb = bstartD[b], ee = bstartD[b+1];
    int ne = ee - eb;

    for (int i = tid; i < ne; i += 256){
        int pr = pairs[eb + i];
        atomicAdd(&lcnt[pr & 63], 1);
    }
    __syncthreads();
    if (tid < 64){
        int mt = (tid < BPB) ? lcnt[tid] : 0;
        int v = (mt + 3) & ~3;
        int sI = v;
        for (int off=1; off<64; off<<=1){
            int t = __shfl_up(sI, off);
            if (tid >= off) sI += t;
        }
        if (tid < BPB){
            lstart[tid] = sI - v;
            lofs[tid]   = (unsigned)(sI - v);
            if (tid == BPB-1) lstart[BPB] = sI;
        }
    }
    __syncthreads();
    for (int i = tid; i < ne; i += 256){
        int pr = pairs[eb + i];
        unsigned pos = atomicAdd(&lofs[pr & 63], 1u);
        lsrc[pos < ECAP ? pos : ECAP-1] = pr >> 6;
    }
    __syncthreads();

    int ptot = lstart[BPB];
    for (int i = tid; i < ptot; i += 256) gsrc[b*ECAP + i] = lsrc[i];
    if (tid <= BPB){
        int mt = (tid < BPB) ? lcnt[tid] : 0;
        glh[b*64 + tid] = (lstart[tid] & 0xFFFF) | (mt << 16);
    }

    int lane = tid & 63, wid = tid >> 6;
    int q  = lane >> 4;
    int c4 = lane & 15;

    for (int nl = wid; nl < BPB; nl += 4){
        int node = nodeBase + nl;
        int s0 = lstart[nl];
        int m4 = lstart[nl+1] - s0;
        int mt = lcnt[nl];

        float a0=0.f, a1f=0.f, a2=0.f, a3=0.f;
        int j = 0;
        for (; j + 16 <= m4; j += 16){
            int sa = lsrc[s0 + j + q];
            int sb = lsrc[s0 + j + 4 + q];
            int sc = lsrc[s0 + j + 8 + q];
            int sd = lsrc[s0 + j + 12 + q];
            uint2 va = *(const uint2*)(hb + ((size_t)sa<<6) + (c4<<2));
            uint2 vb = *(const uint2*)(hb + ((size_t)sb<<6) + (c4<<2));
            uint2 vc = *(const uint2*)(hb + ((size_t)sc<<6) + (c4<<2));
            uint2 vd = *(const uint2*)(hb + ((size_t)sd<<6) + (c4<<2));
            a0  += __uint_as_float((va.x & 0xffffu) << 16) + __uint_as_float((vb.x & 0xffffu) << 16)
                 + __uint_as_float((vc.x & 0xffffu) << 16) + __uint_as_float((vd.x & 0xffffu) << 16);
            a1f += __uint_as_float(va.x & 0xffff0000u) + __uint_as_float(vb.x & 0xffff0000u)
                 + __uint_as_float(vc.x & 0xffff0000u) + __uint_as_float(vd.x & 0xffff0000u);
            a2  += __uint_as_float((va.y & 0xffffu) << 16) + __uint_as_float((vb.y & 0xffffu) << 16)
                 + __uint_as_float((vc.y & 0xffffu) << 16) + __uint_as_float((vd.y & 0xffffu) << 16);
            a3  += __uint_as_float(va.y & 0xffff0000u) + __uint_as_float(vb.y & 0xffff0000u)
                 + __uint_as_float(vc.y & 0xffff0000u) + __uint_as_float(vd.y & 0xffff0000u);
        }
        for (; j < m4; j += 4){
            int sa = lsrc[s0 + j + q];
            uint2 va = *(const uint2*)(hb + ((size_t)sa<<6) + (c4<<2));
            a0  += __uint_as_float((va.x & 0xffffu) << 16);
            a1f += __uint_as_float(va.x & 0xffff0000u);
            a2  += __uint_as_float((va.y & 0xffffu) << 16);
            a3  += __uint_as_float(va.y & 0xffff0000u);
        }
        a0  += __shfl_xor(a0, 16);  a0  += __shfl_xor(a0, 32);
        a1f += __shfl_xor(a1f, 16); a1f += __shfl_xor(a1f, 32);
        a2  += __shfl_xor(a2, 16);  a2  += __shfl_xor(a2, 32);
        a3  += __shfl_xor(a3, 16);  a3  += __shfl_xor(a3, 32);

        float dnv = rsqrtf((float)max(mt, 1));
        float snv = sn[node];
        float r0 = fmaxf(fmaf(a0,  dnv, b1s[(c4<<2)+0]), 0.f) * snv;
        float r1 = fmaxf(fmaf(a1f, dnv, b1s[(c4<<2)+1]), 0.f) * snv;
        float r2 = fmaxf(fmaf(a2,  dnv, b1s[(c4<<2)+2]), 0.f) * snv;
        float r3 = fmaxf(fmaf(a3,  dnv, b1s[(c4<<2)+3]), 0.f) * snv;
        if (q == 0){
            *(float4*)(&a1s[nl][c4<<2]) = make_float4(r0, r1, r2, r3);
        }
    }
    __syncthreads();

    for (int i = tid; i < BPB*10; i += 256){
        int nl = i / 10;
        int c  = i - nl*10;
        int node = nodeBase + nl;
        if (node < N){
            const float4* ap = (const float4*)(&a1s[nl][0]);
            const float4* wp = (const float4*)(&w2t[c][0]);
            float acc = 0.f;
            #pragma unroll
            for (int p=0;p<16;p++){
                float4 a = ap[p]; float4 w = wp[p];
                acc = fmaf(a.x, w.x, fmaf(a.y, w.y, fmaf(a.z, w.z, fmaf(a.w, w.w, acc))));
            }
            h2[(size_t)node*16 + c] = acc;
        }
    }
}

// ---------------- k_pool2 ----------------
__global__ __launch_bounds__(256) void k_pool2(const int* __restrict__ gsrc, const int* __restrict__ glh,
                                               const float* __restrict__ h2, const int* __restrict__ n2g,
                                               float* __restrict__ pooled, int N){
    __shared__ float accS[NG*10];
    int tid = threadIdx.x;
    for (int i=tid; i<NG*10; i+=256) accS[i] = 0.f;
    __syncthreads();
    int b = blockIdx.x;
    int nodeBase = b*BPB;
    int lane = tid & 63, wid = tid >> 6;
    int e6 = lane/10, c = lane - e6*10;
    bool active = (lane < 60);

    for (int nl = wid; nl < BPB; nl += 4){
        int node = nodeBase + nl;
        int cur = glh[b*64 + nl];
        int nxt = glh[b*64 + nl + 1];
        int base = b*ECAP + (cur & 0xFFFF);
        int m4   = (nxt & 0xFFFF) - (cur & 0xFFFF);
        int mt   = cur >> 16;
        float acc = 0.f;
        for (int j = 0; j < m4; j += 6){
            int idx = j + e6;
            int idxc = (idx < m4) ? idx : (m4-1);
            int srcn = gsrc[base + idxc];
            float v = h2[(size_t)srcn*16 + c];
            if (active && idx < m4) acc += v;
        }
        float t0 = __shfl(acc, lane+30); if (lane < 30) acc += t0;
        float t1 = __shfl(acc, lane+10);
        float t2 = __shfl(acc, lane+20);
        if (lane < 10){
            acc += t1 + t2;
            float dnv = rsqrtf((float)max(mt, 1));
            int g = n2g[node];
            atomicAdd(&accS[g*10 + lane], dnv*acc);
        }
    }
    __syncthreads();
    int g0 = n2g[nodeBase], g1 = n2g[nodeBase + BPB - 1];
    int lo = g0*10, hi = g1*10 + 10;
    for (int i = lo + tid; i < hi; i += 256)
        atomicAdd(&pooled[i], accS[i]);
}

// ---------------- final ----------------
__global__ void k_out(const float* __restrict__ pooled, const int* __restrict__ gstart,
                      const float* __restrict__ b2, float* __restrict__ out){
    int i = blockIdx.x*blockDim.x + threadIdx.x;
    if (i < NG*10){
        int g = i/10, c = i - g*10;
        float cnt = (float)max(gstart[g+1] - gstart[g], 1);
        out[i] = pooled[i]/cnt + b2[c];
    }
}

extern "C" void kernel_launch(void* const* d_in, const int* in_sizes, int n_in,
                              void* d_out, int out_size, void* d_ws, size_t ws_size,
                              hipStream_t stream) {
    const float* x    = (const float*)d_in[0];
    const int*   esrc = (const int*)d_in[1];
    const int*   edst = (const int*)d_in[2];
    const int*   n2g  = (const int*)d_in[3];
    const float* W1   = (const float*)d_in[5];
    const float* b1   = (const float*)d_in[6];
    const float* W2   = (const float*)d_in[7];
    const float* b2   = (const float*)d_in[8];
    float* out = (float*)d_out;
    const int N = in_sizes[3];
    const int E = in_sizes[1];

    char* ws = (char*)d_ws;
    size_t off = 0;
    auto alloc = [&](size_t bytes) -> void* {
        void* p = ws + off;
        off = (off + bytes + 255) & ~(size_t)255;
        return p;
    };
    float* pooled  = (float*)alloc(NG*10*4);
    int*   cntD    = (int*)alloc((size_t)GPART*NBUK2*4);
    int*   cntS    = (int*)alloc((size_t)GPART*NBUK2*4);
    int*   sliceD  = (int*)alloc((size_t)NSLICE*NBUK2*4);
    int*   sliceS  = (int*)alloc((size_t)NSLICE*NBUK2*4);
    int*   bstartD = (int*)alloc((NBUK+1)*4);
    int*   bstartS = (int*)alloc((NBUK+1)*4);
    int*   pairs   = (int*)alloc((size_t)E*4);
    unsigned char* srcb = (unsigned char*)alloc((size_t)E);
    int*   gsrc    = (int*)alloc((size_t)NBUK*ECAP*4);
    int*   glh     = (int*)alloc((size_t)NBUK*64*4);
    float* sn      = (float*)alloc((size_t)N*4);
    int*   gstart  = (int*)alloc((size_t)(NG+1)*4);
    short* Wb      = (short*)alloc((size_t)512*64*2);
    unsigned short* hb = (unsigned short*)alloc((size_t)(N+1)*64*2);
    float* h2      = (float*)alloc((size_t)(N+1)*16*4);

    k_start<<<dim3(GPART+PREPB+ZEROB+GSTB), dim3(256), 0, stream>>>(
        esrc, edst, cntD, cntS, E, W1, Wb, pooled, hb, h2, n2g, gstart, N);
    k_scanCa<<<dim3(64), dim3(256), 0, stream>>>(cntD, cntS, sliceD, sliceS);
    k_scanB<<<dim3(1), dim3(1024), 0, stream>>>(sliceD, sliceS, bstartD, bstartS);
    k_scanCb<<<dim3(64), dim3(256), 0, stream>>>(cntD, cntS, sliceD, sliceS, bstartD, bstartS);
    k_scatter<<<dim3(GPART), dim3(256), 0, stream>>>(esrc, edst, cntD, cntS, pairs, srcb, E);
    k_outdeg<<<dim3(NBUK), dim3(256), 0, stream>>>(srcb, bstartS, sn, N);

    k_gemm1<<<dim3((N+127)/128), dim3(256), 0, stream>>>(x, Wb, sn, hb, N);

    k_agg<<<dim3(NBUK), dim3(256), 0, stream>>>(pairs, bstartD, hb, sn, b1, W2, h2, gsrc, glh, N);
    k_pool2<<<dim3(NBUK), dim3(256), 0, stream>>>(gsrc, glh, h2, n2g, pooled, N);
    k_out<<<dim3(3), dim3(256), 0, stream>>>(pooled, gstart, b2, out);
}